// Round 6
// baseline (93018.524 us; speedup 1.0000x reference)
//
#include <hip/hip_runtime.h>

#define SEQ  512
#define IDIM 256
#define H    1024
#define NC   128
#define B    256
#define NBLK 256   // 16 groups x 16 WGs (16 rows x 64 cols each)

typedef __attribute__((ext_vector_type(8))) short bh8;
typedef __attribute__((ext_vector_type(4))) float f4;
typedef __attribute__((ext_vector_type(4))) int i4;

__device__ __forceinline__ float sigf(float x) { return 1.0f / (1.0f + __expf(-x)); }

__device__ __forceinline__ unsigned short bf16r(float v) {
    unsigned u = __builtin_bit_cast(unsigned, v);
    u += 0x7fffu + ((u >> 16) & 1u);
    return (unsigned short)(u >> 16);
}

template<bool V> struct BoolT { static constexpr bool value = V; };

// ---------------- token tables: FF/II/OO = emb@W*x.T + b*, G = sigmoid(emb@Wcx.T + bc) ----
__global__ __launch_bounds__(256) void tables_kernel(
    const float* __restrict__ emb,
    const float* __restrict__ Wcx, const float* __restrict__ bc,
    const float* __restrict__ Wix, const float* __restrict__ bi,
    const float* __restrict__ Wfx, const float* __restrict__ bf,
    const float* __restrict__ Wox, const float* __restrict__ bo,
    float* __restrict__ FF, float* __restrict__ II,
    float* __restrict__ OO, float* __restrict__ G)
{
    const int k = blockIdx.x;
    const int h = blockIdx.y * 256 + threadIdx.x;
    __shared__ float e[IDIM];
    e[threadIdx.x] = emb[k * IDIM + threadIdx.x];
    __syncthreads();
    const float4* e4  = (const float4*)e;
    const float4* wf4 = (const float4*)(Wfx + (size_t)h * IDIM);
    const float4* wi4 = (const float4*)(Wix + (size_t)h * IDIM);
    const float4* wo4 = (const float4*)(Wox + (size_t)h * IDIM);
    const float4* wc4 = (const float4*)(Wcx + (size_t)h * IDIM);
    float aF = 0.f, aI = 0.f, aO = 0.f, aC = 0.f;
#pragma unroll 4
    for (int i = 0; i < IDIM / 4; i++) {
        float4 ev = e4[i];
        float4 a = wf4[i]; aF += ev.x * a.x + ev.y * a.y + ev.z * a.z + ev.w * a.w;
        float4 b = wi4[i]; aI += ev.x * b.x + ev.y * b.y + ev.z * b.z + ev.w * b.w;
        float4 c = wo4[i]; aO += ev.x * c.x + ev.y * c.y + ev.z * c.z + ev.w * c.w;
        float4 d = wc4[i]; aC += ev.x * d.x + ev.y * d.y + ev.z * d.z + ev.w * d.w;
    }
    const int o = k * H + h;
    FF[o] = aF + bf[h];
    II[o] = aI + bi[h];
    OO[o] = aO + bo[h];
    G[o]  = sigf(aC + bc[h]);
}

// ---------------- weight fp32 -> bf16 swizzled for MFMA B-fragments -----------------------
__global__ __launch_bounds__(256) void swz_kernel(const float* __restrict__ W,
                                                  unsigned short* __restrict__ D)
{
    int g = blockIdx.x * 256 + threadIdx.x;     // 0..131071
    int h  = g >> 7;
    int kc = (g & 127) << 3;
    const float4* s = (const float4*)(W + (size_t)h * H + kc);
    float4 a = s[0], b = s[1];
    unsigned short tmp[8] = { bf16r(a.x), bf16r(a.y), bf16r(a.z), bf16r(a.w),
                              bf16r(b.x), bf16r(b.y), bf16r(b.z), bf16r(b.w) };
    int nb = h >> 4, kb = kc >> 5, quad = (kc >> 3) & 3;
    int lane = (h & 15) + (quad << 4);
    bh8 v;
#pragma unroll
    for (int j = 0; j < 8; j++) v[j] = (short)tmp[j];
    *(bh8*)(D + (size_t)((nb * 32 + kb) * 512 + lane * 8)) = v;
}

// ------- persistent recurrence: r12 protocol + EMPIRICALLY-PROBED XCD-local scope --------
// R2/R4/R5 post-mortem: trusting HW_REG_XCC_ID to prove XCD purity can pass SPURIOUSLY
// (masked/virtualized register) -> local-scope exchange across XCDs -> invisible flags ->
// timeout. This round verifies VISIBILITY, not placement:
//   probe:    each WG publishes 1 via the exact local primitive (no-sc atomic swap);
//             wave0 spins a BOUNDED 2048 iters on peers' probes via sc0 loads.
//             Pure group -> all seen in a few iters. Impure group -> every WG misses the
//             other side (not coherent) -> all time out. Verdict is topology-uniform.
//   decide:   verdicts made unanimous via a device-scope (sc1) decision round — proven
//             R0 semantics. Group mode = AND of its 16 decisions.
//   body:     LOC -> no-sc atomic-swap writes (perform at own XCD L2, ~250cy) + sc0
//             polls/stages (L1-bypass, L2 hit). Else -> byte-identical r12 sc1 protocol.
// Every wait is bounded, probed, or R0-liveness-class. Worst case = R0 + ~0.3ms.
__global__ __launch_bounds__(256, 1) void persist_kernel(
    const unsigned short* __restrict__ Wf, const unsigned short* __restrict__ Wi,
    const unsigned short* __restrict__ Wo,
    const float* __restrict__ FF, const float* __restrict__ II,
    const float* __restrict__ OO, const float* __restrict__ G,
    const int* __restrict__ x,
    unsigned short* c16a, unsigned short* c16b,
    float* __restrict__ hb, int* flags, unsigned* probes, unsigned* decis)
{
    const int blk = blockIdx.x;         // 0..255
    const int tid  = threadIdx.x;
    const int wave = tid >> 6;          // wave owns 16 cols, all 16 group rows
    const int lane = tid & 63;
    const int l15 = lane & 15, quad = lane >> 4;

    // XCD-friendly remap (bijective: blk <-> (rt,nt)); under round-robin bid->XCD
    // (xcd = blk&7) each group's 16 WGs share one XCD. Purity is PROBED, not assumed.
    const int xg = blk & 7;
    const int jj = blk >> 3;            // 0..31
    const int rt = xg * 2 + (jj & 1);   // group 0..15 (16 batch rows)
    const int nt = jj >> 1;             // 64-col tile 0..15 within group

    __shared__ unsigned short cs[16 * 1024];   // 32 KB, XOR-swizzled 16B granules

    // ---- A) publish probe via the LOCAL primitive under test (no sc bits) ----
    if (tid == 0) {
        unsigned one = 1u;
        unsigned* pp = probes + rt * 16 + nt;
        asm volatile("global_atomic_swap %0, %1, off" :: "v"(pp), "v"(one) : "memory");
    }

    const int row0 = rt * 16;
    const int abase = l15 * 1024;              // A-frag row (m = l15)
    const int asw = l15 & 7;
    const int hcol = nt * 64 + wave * 16 + l15;
    const int nb = nt * 4 + wave;              // 16-col weight block 0..63

    const unsigned short* wfp = Wf + (size_t)nb * 32 * 512 + (size_t)lane * 8;
    const unsigned short* wip = Wi + (size_t)nb * 32 * 512 + (size_t)lane * 8;
    const unsigned short* wop = Wo + (size_t)nb * 32 * 512 + (size_t)lane * 8;

    // ---- B) loop-invariant F/I weight fragments (1 KB/lane) — hides peers' publish ----
    bh8 wf_r[32], wi_r[32];
#pragma unroll
    for (int kt = 0; kt < 32; kt++) {
        wf_r[kt] = *(const bh8*)(wfp + (size_t)kt * 512);
        wi_r[kt] = *(const bh8*)(wip + (size_t)kt * 512);
    }

    // ---- C) wave0: BOUNDED probe spin with sc0 loads (the LOC read primitive) ----
    if (wave == 0) {
        bool ok = false;
        const unsigned* pp = probes + rt * 16 + (lane & 15);
        for (int it = 0; it < 2048; ++it) {
            unsigned pv;
            asm volatile("global_load_dword %0, %1, off sc0\n\ts_waitcnt vmcnt(0)"
                         : "=v"(pv) : "v"(pp) : "memory");
            if (__all(pv == 1u)) { ok = true; break; }
        }
        if (tid == 0) {
            unsigned dv = ok ? 1u : 2u;
            unsigned* dp = decis + rt * 16 + nt;
            asm volatile("global_atomic_swap %0, %1, off sc1" :: "v"(dp), "v"(dv) : "memory");
        }
    }

    // ---- D) unanimous decision via device scope (R0-proven semantics) ----
    bool loc;
    {
        const unsigned* dp = decis + rt * 16 + (lane & 15);
        int guard = 0;
        for (;;) {
            unsigned dv;
            asm volatile("global_load_dword %0, %1, off sc0 sc1\n\ts_waitcnt vmcnt(0)"
                         : "=v"(dv) : "v"(dp) : "memory");
            if (__all(dv != 0u)) { loc = __all(dv == 1u); break; }
            if (++guard > (1 << 24)) { loc = false; break; }
        }
    }

    float cn_keep[4] = {0.f, 0.f, 0.f, 0.f};   // fp32 cell state in registers
    int* const myflag = flags + rt * 64 + nt * 4 + wave;   // per-wave flag
    const int* const pf = flags + rt * 64 + lane;          // 64 group flags, coalesced

    auto body = [&](auto lc) {
        constexpr bool LOC = decltype(lc)::value;
        // asm operands must be lambda-locals (hipcc rejects by-ref-captured names)
        const int* const pf_l = pf;
        int* const mf_l = myflag;
        // LOC guard small: a (theoretically impossible) probe false-positive then yields
        // a fast wrong-answer instead of a 40s hang. Fallback keeps R0's 1<<20.
        const int PGUARD = LOC ? (1 << 14) : (1 << 20);
        for (int s = 0; s < SEQ; s++) {
            const unsigned short* cur16 = (s & 1) ? c16b : c16a;
            unsigned short*       nxt16 = (s & 1) ? c16a : c16b;

            // token/table prefetch — in flight while we poll
            float ffv[4], iiv[4], ggv[4];
#pragma unroll
            for (int r = 0; r < 4; r++) {
                int b = row0 + quad * 4 + r;
                int tok = x[b * SEQ + s];
                ffv[r] = FF[tok * H + hcol];
                iiv[r] = II[tok * H + hcol];
                ggv[r] = G[tok * H + hcol];
            }

            f4 accF = {0.f, 0.f, 0.f, 0.f}, accI = {0.f, 0.f, 0.f, 0.f};
            if (s > 0) {
                // per-wave poll: every wave checks all 64 group flags itself
                {
                    int guard = 0;
                    for (;;) {
                        int fv;
                        if (LOC)
                            asm volatile("global_load_dword %0, %1, off sc0\n\ts_waitcnt vmcnt(0)"
                                         : "=v"(fv) : "v"(pf_l) : "memory");
                        else
                            asm volatile("global_load_dword %0, %1, off sc0 sc1\n\ts_waitcnt vmcnt(0)"
                                         : "=v"(fv) : "v"(pf_l) : "memory");
                        if (__all(fv >= s)) break;
                        if (++guard > PGUARD) break;   // bailout (debug / fast-fail)
                    }
                }
                // stage 16 rows x 2 KB bf16 of c: 8 pipelined loads/lane, ONE waitcnt
                i4 tmp[8];
#pragma unroll
                for (int i = 0; i < 8; i++) {
                    int chunk = i * 256 + tid;           // 0..2047
                    int row = chunk >> 7, g = chunk & 127;
                    const i4* p = (const i4*)(cur16 + (size_t)(row0 + row) * H + g * 8);
                    if (LOC)
                        asm volatile("global_load_dwordx4 %0, %1, off sc0"
                                     : "=v"(tmp[i]) : "v"(p));
                    else
                        asm volatile("global_load_dwordx4 %0, %1, off sc0 sc1"
                                     : "=v"(tmp[i]) : "v"(p));
                }
                asm volatile("s_waitcnt vmcnt(0)" ::: "memory");
#pragma unroll
                for (int i = 0; i < 8; i++) {
                    int chunk = i * 256 + tid;
                    int row = chunk >> 7, g = chunk & 127;
                    *(i4*)(cs + row * 1024 + ((g ^ (row & 7)) << 3)) = tmp[i];
                }
                __syncthreads();   // the ONE per-step WG sync: LDS write -> MFMA read
#pragma unroll
                for (int kt = 0; kt < 32; kt++) {
                    bh8 a = *(const bh8*)(cs + abase + (((kt * 4 + quad) ^ asw) << 3));
                    accF = __builtin_amdgcn_mfma_f32_16x16x32_bf16(a, wf_r[kt], accF, 0, 0, 0);
                    accI = __builtin_amdgcn_mfma_f32_16x16x32_bf16(a, wi_r[kt], accI, 0, 0, 0);
                }
            }

            // epilogue: C/D col=lane&15, row=quad*4+reg; pack 2 cols/dword. Both paths:
            // NON-RETURNING atomic swap (performs AT the cache, never L1-buffered).
            // LOC: no sc bits -> own XCD L2 (probed visible). else: sc1 -> LLC (r12).
#pragma unroll
            for (int r = 0; r < 4; r++) {
                float f = sigf(ffv[r] + accF[r]);
                float i = sigf(iiv[r] + accI[r]);
                float cn = ggv[r] * i + cn_keep[r] * f;
                cn_keep[r] = cn;
                int b = row0 + quad * 4 + r;
                unsigned us = bf16r(cn);
                unsigned ot = (unsigned)__shfl_xor((int)us, 1);
                if (s < SEQ - 1 && (lane & 1) == 0) {
                    unsigned dw = us | (ot << 16);
                    unsigned* p = (unsigned*)(nxt16 + (size_t)b * H + hcol);
                    if (LOC)
                        asm volatile("global_atomic_swap %0, %1, off"
                                     :: "v"(p), "v"(dw) : "memory");
                    else
                        asm volatile("global_atomic_swap %0, %1, off sc1"
                                     :: "v"(p), "v"(dw) : "memory");
                }
            }

            if (s < SEQ - 1) {
                // per-wave arrive: drain MY swaps (completed at scope point), post MY flag
                asm volatile("s_waitcnt vmcnt(0)" ::: "memory");
                if (lane == 0) {
                    int v = s + 1;
                    if (LOC)
                        asm volatile("global_atomic_swap %0, %1, off"
                                     :: "v"(mf_l), "v"(v) : "memory");
                    else
                        asm volatile("global_atomic_swap %0, %1, off sc1"
                                     :: "v"(mf_l), "v"(v) : "memory");
                }
            }
        }
    };
    if (loc) body(BoolT<true>{});
    else     body(BoolT<false>{});

    // o-gate: c_{SEQ-2} still staged in LDS (reference: o uses pre-update cell);
    // Wo streamed from L2 (used once)
    f4 accO = {0.f, 0.f, 0.f, 0.f};
#pragma unroll 4
    for (int kt = 0; kt < 32; kt++) {
        bh8 a  = *(const bh8*)(cs + abase + (((kt * 4 + quad) ^ asw) << 3));
        bh8 bo = *(const bh8*)(wop + (size_t)kt * 512);
        accO = __builtin_amdgcn_mfma_f32_16x16x32_bf16(a, bo, accO, 0, 0, 0);
    }
#pragma unroll
    for (int r = 0; r < 4; r++) {
        int b = row0 + quad * 4 + r;
        int tok = x[b * SEQ + (SEQ - 1)];
        float o = sigf(OO[tok * H + hcol] + accO[r]);
        hb[(size_t)b * H + hcol] = tanhf(cn_keep[r]) * o;
    }
}

// ---------------- p = h @ Wph.T + bp ; out = log_softmax(p) -------------------------------
__global__ __launch_bounds__(128) void out_kernel(
    const float* __restrict__ hbuf, const float* __restrict__ Wph,
    const float* __restrict__ bp, float* __restrict__ out)
{
    const int b = blockIdx.x;
    const int j = threadIdx.x;
    __shared__ float hs[H];
    for (int t = j; t < H; t += 128) hs[t] = hbuf[(size_t)b * H + t];
    __syncthreads();
    const float4* w4 = (const float4*)(Wph + (size_t)j * H);
    const float4* h4 = (const float4*)hs;
    float acc = bp[j];
#pragma unroll 4
    for (int k = 0; k < H / 4; k++) {
        float4 a = w4[k], v = h4[k];
        acc += a.x * v.x + a.y * v.y + a.z * v.z + a.w * v.w;
    }
    __shared__ float red[128];
    red[j] = acc; __syncthreads();
    for (int off = 64; off > 0; off >>= 1) { if (j < off) red[j] = fmaxf(red[j], red[j + off]); __syncthreads(); }
    float m = red[0]; __syncthreads();
    red[j] = __expf(acc - m); __syncthreads();
    for (int off = 64; off > 0; off >>= 1) { if (j < off) red[j] += red[j + off]; __syncthreads(); }
    float lse = m + __logf(red[0]);
    out[(size_t)b * NC + j] = acc - lse;
}

extern "C" void kernel_launch(void* const* d_in, const int* in_sizes, int n_in,
                              void* d_out, int out_size, void* d_ws, size_t ws_size,
                              hipStream_t stream)
{
    const int*   x   = (const int*)d_in[0];
    const float* emb = (const float*)d_in[1];
    const float* Wcx = (const float*)d_in[2];
    const float* bc  = (const float*)d_in[3];
    const float* Wix = (const float*)d_in[4];
    const float* Wih = (const float*)d_in[5];
    const float* bi  = (const float*)d_in[6];
    const float* Wfx = (const float*)d_in[7];
    const float* Wfh = (const float*)d_in[8];
    const float* bf  = (const float*)d_in[9];
    const float* Wox = (const float*)d_in[10];
    const float* Woh = (const float*)d_in[11];
    const float* bo  = (const float*)d_in[12];
    const float* Wph = (const float*)d_in[13];
    const float* bp  = (const float*)d_in[14];
    float* out = (float*)d_out;

    char* wsb = (char*)d_ws;
    float* FF = (float*)(wsb + 0);                         // 512 KB
    float* II = (float*)(wsb + (512 << 10));
    float* OO = (float*)(wsb + (1024 << 10));
    float* G  = (float*)(wsb + (1536 << 10));
    float* hb = (float*)(wsb + (2048 << 10));              // 1 MB
    int*   flags  = (int*)(wsb + (3072 << 10));            // 4 KB (16 groups x 64 wave-flags)
    unsigned* probes = (unsigned*)(wsb + (3072 << 10) + 4096);   // 1 KB (16x16 probe slots)
    unsigned* decis  = (unsigned*)(wsb + (3072 << 10) + 5120);   // 1 KB (16x16 decisions)
    unsigned short* Wf_sw = (unsigned short*)(wsb + (4096 << 10));   // 2 MB each
    unsigned short* Wi_sw = (unsigned short*)(wsb + (6144 << 10));
    unsigned short* Wo_sw = (unsigned short*)(wsb + (8192 << 10));
    unsigned short* c16a  = (unsigned short*)(wsb + (10240 << 10));  // 512 KB each
    unsigned short* c16b  = (unsigned short*)(wsb + (10752 << 10));

    (void)hipMemsetAsync(flags, 0, 4096 + 2048, stream);   // flags + probes + decisions

    tables_kernel<<<dim3(NC, 4), 256, 0, stream>>>(emb, Wcx, bc, Wix, bi, Wfx, bf, Wox, bo,
                                                   FF, II, OO, G);
    swz_kernel<<<512, 256, 0, stream>>>(Wfh, Wf_sw);
    swz_kernel<<<512, 256, 0, stream>>>(Wih, Wi_sw);
    swz_kernel<<<512, 256, 0, stream>>>(Woh, Wo_sw);

    persist_kernel<<<NBLK, 256, 0, stream>>>(Wf_sw, Wi_sw, Wo_sw, FF, II, OO, G, x,
                                             c16a, c16b, hb, flags, probes, decis);

    out_kernel<<<B, 128, 0, stream>>>(hb, Wph, bp, out);
}

// Round 7
// 5595.257 us; speedup vs baseline: 16.6245x; 16.6245x over previous
//
#include <hip/hip_runtime.h>

#define SEQ  512
#define IDIM 256
#define H    1024
#define NC   128
#define B    256
#define NBLK 128   // 8 sets x 16 WGs; each WG serves TWO groups (A,B) on 64 cols

typedef __attribute__((ext_vector_type(8))) short bh8;
typedef __attribute__((ext_vector_type(4))) float f4;
typedef __attribute__((ext_vector_type(4))) int i4;

__device__ __forceinline__ float sigf(float x) { return 1.0f / (1.0f + __expf(-x)); }

__device__ __forceinline__ unsigned short bf16r(float v) {
    unsigned u = __builtin_bit_cast(unsigned, v);
    u += 0x7fffu + ((u >> 16) & 1u);
    return (unsigned short)(u >> 16);
}

// ---------------- token tables: FF/II/OO = emb@W*x.T + b*, G = sigmoid(emb@Wcx.T + bc) ----
__global__ __launch_bounds__(256) void tables_kernel(
    const float* __restrict__ emb,
    const float* __restrict__ Wcx, const float* __restrict__ bc,
    const float* __restrict__ Wix, const float* __restrict__ bi,
    const float* __restrict__ Wfx, const float* __restrict__ bf,
    const float* __restrict__ Wox, const float* __restrict__ bo,
    float* __restrict__ FF, float* __restrict__ II,
    float* __restrict__ OO, float* __restrict__ G)
{
    const int k = blockIdx.x;
    const int h = blockIdx.y * 256 + threadIdx.x;
    __shared__ float e[IDIM];
    e[threadIdx.x] = emb[k * IDIM + threadIdx.x];
    __syncthreads();
    const float4* e4  = (const float4*)e;
    const float4* wf4 = (const float4*)(Wfx + (size_t)h * IDIM);
    const float4* wi4 = (const float4*)(Wix + (size_t)h * IDIM);
    const float4* wo4 = (const float4*)(Wox + (size_t)h * IDIM);
    const float4* wc4 = (const float4*)(Wcx + (size_t)h * IDIM);
    float aF = 0.f, aI = 0.f, aO = 0.f, aC = 0.f;
#pragma unroll 4
    for (int i = 0; i < IDIM / 4; i++) {
        float4 ev = e4[i];
        float4 a = wf4[i]; aF += ev.x * a.x + ev.y * a.y + ev.z * a.z + ev.w * a.w;
        float4 b = wi4[i]; aI += ev.x * b.x + ev.y * b.y + ev.z * b.z + ev.w * b.w;
        float4 c = wo4[i]; aO += ev.x * c.x + ev.y * c.y + ev.z * c.z + ev.w * c.w;
        float4 d = wc4[i]; aC += ev.x * d.x + ev.y * d.y + ev.z * d.z + ev.w * d.w;
    }
    const int o = k * H + h;
    FF[o] = aF + bf[h];
    II[o] = aI + bi[h];
    OO[o] = aO + bo[h];
    G[o]  = sigf(aC + bc[h]);
}

// ---------------- weight fp32 -> bf16 swizzled for MFMA B-fragments -----------------------
__global__ __launch_bounds__(256) void swz_kernel(const float* __restrict__ W,
                                                  unsigned short* __restrict__ D)
{
    int g = blockIdx.x * 256 + threadIdx.x;     // 0..131071
    int h  = g >> 7;
    int kc = (g & 127) << 3;
    const float4* s = (const float4*)(W + (size_t)h * H + kc);
    float4 a = s[0], b = s[1];
    unsigned short tmp[8] = { bf16r(a.x), bf16r(a.y), bf16r(a.z), bf16r(a.w),
                              bf16r(b.x), bf16r(b.y), bf16r(b.z), bf16r(b.w) };
    int nb = h >> 4, kb = kc >> 5, quad = (kc >> 3) & 3;
    int lane = (h & 15) + (quad << 4);
    bh8 v;
#pragma unroll
    for (int j = 0; j < 8; j++) v[j] = (short)tmp[j];
    *(bh8*)(D + (size_t)((nb * 32 + kb) * 512 + lane * 8)) = v;
}

// helper macros (R0-proven primitives only: sc1 atomics, sc0 sc1 loads)
#define ATOMSW(p_, v_) asm volatile("global_atomic_swap %0, %1, off sc1" :: "v"(p_), "v"(v_) : "memory")
#define POLL(pf_, thr_)                                                                     \
    { int guard_ = 0;                                                                       \
      for (;;) { int fv_;                                                                   \
        asm volatile("global_load_dword %0, %1, off sc0 sc1\n\ts_waitcnt vmcnt(0)"          \
                     : "=v"(fv_) : "v"(pf_) : "memory");                                    \
        if (__all(fv_ >= (thr_))) break;                                                    \
        if (++guard_ > (1 << 20)) break; } }
#define STAGE_ISSUE(tmp_, cur_, row0_)                                                      \
    _Pragma("unroll")                                                                       \
    for (int i_ = 0; i_ < 8; i_++) {                                                        \
        int chunk_ = i_ * 256 + tid;                                                        \
        int row_ = chunk_ >> 7, g_ = chunk_ & 127;                                          \
        const i4* p_ = (const i4*)((cur_) + (size_t)((row0_) + row_) * H + g_ * 8);         \
        asm volatile("global_load_dwordx4 %0, %1, off sc0 sc1" : "=v"(tmp_[i_]) : "v"(p_)); }
#define LDS_WRITE(cs_, tmp_)                                                                \
    _Pragma("unroll")                                                                       \
    for (int i_ = 0; i_ < 8; i_++) {                                                        \
        int chunk_ = i_ * 256 + tid;                                                        \
        int row_ = chunk_ >> 7, g_ = chunk_ & 127;                                          \
        *(i4*)((cs_) + row_ * 1024 + ((g_ ^ (row_ & 7)) << 3)) = tmp_[i_]; }
#define LOAD_TABLES(row0_, s_, ffv_, iiv_, ggv_)                                            \
    _Pragma("unroll")                                                                       \
    for (int r_ = 0; r_ < 4; r_++) {                                                        \
        int b_ = (row0_) + quad * 4 + r_;                                                   \
        int tok_ = x[b_ * SEQ + (s_)];                                                      \
        ffv_[r_] = FF[tok_ * H + hcol];                                                     \
        iiv_[r_] = II[tok_ * H + hcol];                                                     \
        ggv_[r_] = G[tok_ * H + hcol]; }
#define MFMA32(cs_, accF_, accI_)                                                           \
    _Pragma("unroll")                                                                       \
    for (int kt_ = 0; kt_ < 32; kt_++) {                                                    \
        bh8 a_ = *(const bh8*)((cs_) + abase + (((kt_ * 4 + quad) ^ asw) << 3));            \
        accF_ = __builtin_amdgcn_mfma_f32_16x16x32_bf16(a_, wf_r[kt_], accF_, 0, 0, 0);     \
        accI_ = __builtin_amdgcn_mfma_f32_16x16x32_bf16(a_, wi_r[kt_], accI_, 0, 0, 0); }
// gates for step; writes c to nxt_ when do_store_
#define EPILOGUE(ffv_, iiv_, ggv_, accF_, accI_, cn_, row0_, nxt_, do_store_)               \
    _Pragma("unroll")                                                                       \
    for (int r_ = 0; r_ < 4; r_++) {                                                        \
        float f_ = sigf(ffv_[r_] + accF_[r_]);                                              \
        float i_ = sigf(iiv_[r_] + accI_[r_]);                                              \
        float cn2_ = ggv_[r_] * i_ + cn_[r_] * f_;                                          \
        cn_[r_] = cn2_;                                                                     \
        int b_ = (row0_) + quad * 4 + r_;                                                   \
        unsigned us_ = bf16r(cn2_);                                                         \
        unsigned ot_ = (unsigned)__shfl_xor((int)us_, 1);                                   \
        if ((do_store_) && (lane & 1) == 0) {                                               \
            unsigned dw_ = us_ | (ot_ << 16);                                               \
            unsigned* p_ = (unsigned*)((nxt_) + (size_t)b_ * H + hcol);                     \
            ATOMSW(p_, dw_); } }

// ------- persistent recurrence: TWO-GROUP ANTIPHASE PIPELINE (pure R0 semantics) ---------
// R6 verdict: sc0-only re-read polling never sees L2 updates (L1 not bypassed on re-read)
// -> XCD-local scope abandoned. This kernel keeps the proven sc1/sc0-sc1 protocol and
// instead HIDES the ~8k-cy exchange chain: each WG serves two independent batch groups
// (A=2*set, B=2*set+1) on the same 64 columns (weight frags shared), scheduled in
// antiphase so A's drain/flag/observe/stage latency overlaps B's LDS+MFMA and vice
// versa. 2 vmcnt(0) per iteration, each draining {stages + tables + other-group atomics}
// in one shot. Flag slack before each poll ~= one LDS+sync+MFMA block (~1kcy).
__global__ __launch_bounds__(256, 1) void persist_kernel(
    const unsigned short* __restrict__ Wf, const unsigned short* __restrict__ Wi,
    const unsigned short* __restrict__ Wo,
    const float* __restrict__ FF, const float* __restrict__ II,
    const float* __restrict__ OO, const float* __restrict__ G,
    const int* __restrict__ x,
    unsigned short* c16a, unsigned short* c16b,
    float* __restrict__ hb, int* flags)
{
    const int blk = blockIdx.x;         // 0..127
    const int set = blk >> 4;           // 0..7
    const int nt  = blk & 15;           // 64-col tile
    const int gA = set * 2, gB = set * 2 + 1;
    const int rowA0 = gA * 16, rowB0 = gB * 16;
    const int tid  = threadIdx.x;
    const int wave = tid >> 6;
    const int lane = tid & 63;
    const int l15 = lane & 15, quad = lane >> 4;

    __shared__ unsigned short csA[16 * 1024];   // 32 KB per group tile, XOR-swizzled
    __shared__ unsigned short csB[16 * 1024];

    const int abase = l15 * 1024;
    const int asw = l15 & 7;
    const int hcol = nt * 64 + wave * 16 + l15;
    const int nb = nt * 4 + wave;

    const unsigned short* wfp = Wf + (size_t)nb * 32 * 512 + (size_t)lane * 8;
    const unsigned short* wip = Wi + (size_t)nb * 32 * 512 + (size_t)lane * 8;
    const unsigned short* wop = Wo + (size_t)nb * 32 * 512 + (size_t)lane * 8;

    // loop-invariant F/I weight fragments — SHARED by both groups (same columns)
    bh8 wf_r[32], wi_r[32];
#pragma unroll
    for (int kt = 0; kt < 32; kt++) {
        wf_r[kt] = *(const bh8*)(wfp + (size_t)kt * 512);
        wi_r[kt] = *(const bh8*)(wip + (size_t)kt * 512);
    }

    int* const mfA = flags + gA * 64 + nt * 4 + wave;
    const int* const pfA = flags + gA * 64 + lane;
    int* const mfB = flags + gB * 64 + nt * 4 + wave;
    const int* const pfB = flags + gB * 64 + lane;

    float cnA[4] = {0.f, 0.f, 0.f, 0.f}, cnB[4] = {0.f, 0.f, 0.f, 0.f};
    f4 accFA = {0,0,0,0}, accIA = {0,0,0,0};
    f4 accFB = {0,0,0,0}, accIB = {0,0,0,0};
    float ffvA[4], iivA[4], ggvA[4], ffvB[4], iivB[4], ggvB[4];

    // ---------------- prologue: step 0 for A (B's step-0 epilogue runs at iter-1 top) ----
    LOAD_TABLES(rowA0, 0, ffvA, iivA, ggvA);
    LOAD_TABLES(rowB0, 0, ffvB, iivB, ggvB);     // consumed by epilogue B(0) at iter 1
    EPILOGUE(ffvA, iivA, ggvA, accFA, accIA, cnA, rowA0, c16b, 1);   // c_0^A -> c16b
    asm volatile("s_waitcnt vmcnt(0)" ::: "memory");
    if (lane == 0) { int v = 1; ATOMSW(mfA, v); }

    // ---------------- steady antiphase loop: s = 1..511 ----------------
    for (int s = 1; s < SEQ; s++) {
        const unsigned short* cur16 = (s & 1) ? c16b : c16a;   // holds c_{s-1}
        unsigned short*       nxt16 = (s & 1) ? c16a : c16b;   // receives c_s
        // --- A half ---
        POLL(pfA, s);                          // A flag s posted mid of iter s-1 (slack ~1kcy)
        i4 tmpA[8];
        STAGE_ISSUE(tmpA, cur16, rowA0);       // in flight across epilogue B
        LOAD_TABLES(rowA0, s, ffvA, iivA, ggvA);
        // epilogue B(s-1): acc from MFMA B of prev iter (zeros at s=1); writes into cur16
        // (== nxt(s-1)); safe: poll B(s-1) last iter proved all peers read c_{s-3}.
        EPILOGUE(ffvB, iivB, ggvB, accFB, accIB, cnB, rowB0, cur16, 1);
        asm volatile("s_waitcnt vmcnt(0)" ::: "memory");   // A stages + A tables + B atomics
        if (lane == 0) { int v = s; ATOMSW(mfB, v); }      // B data of step s-1 published
        LDS_WRITE(csA, tmpA);
        __syncthreads();
        accFA = (f4){0,0,0,0}; accIA = (f4){0,0,0,0};
        MFMA32(csA, accFA, accIA);
        // --- B half ---
        POLL(pfB, s);                          // B flag s posted above (slack = LDS+MFMA A)
        i4 tmpB[8];
        STAGE_ISSUE(tmpB, cur16, rowB0);
        LOAD_TABLES(rowB0, s, ffvB, iivB, ggvB);   // consumed by epilogue B(s) next iter
        // epilogue A(s): writes c_s^A into nxt16; skip store at final step
        EPILOGUE(ffvA, iivA, ggvA, accFA, accIA, cnA, rowA0, nxt16, (s < SEQ - 1));
        asm volatile("s_waitcnt vmcnt(0)" ::: "memory");   // B stages + B tables + A atomics
        if (s < SEQ - 1 && lane == 0) { int v = s + 1; ATOMSW(mfA, v); }
        LDS_WRITE(csB, tmpB);
        __syncthreads();
        accFB = (f4){0,0,0,0}; accIB = (f4){0,0,0,0};
        MFMA32(csB, accFB, accIB);
    }

    // pending epilogue B(511): final cell update, no store
    EPILOGUE(ffvB, iivB, ggvB, accFB, accIB, cnB, rowB0, c16a, 0);

    // o-gate for both groups: c_510 tiles still staged in csA/csB; Wo streamed once,
    // each fragment feeds both groups' MFMA.
    f4 accOA = {0,0,0,0}, accOB = {0,0,0,0};
#pragma unroll 4
    for (int kt = 0; kt < 32; kt++) {
        bh8 bo = *(const bh8*)(wop + (size_t)kt * 512);
        bh8 aA = *(const bh8*)(csA + abase + (((kt * 4 + quad) ^ asw) << 3));
        bh8 aB = *(const bh8*)(csB + abase + (((kt * 4 + quad) ^ asw) << 3));
        accOA = __builtin_amdgcn_mfma_f32_16x16x32_bf16(aA, bo, accOA, 0, 0, 0);
        accOB = __builtin_amdgcn_mfma_f32_16x16x32_bf16(aB, bo, accOB, 0, 0, 0);
    }
#pragma unroll
    for (int r = 0; r < 4; r++) {
        int bA = rowA0 + quad * 4 + r;
        int tokA = x[bA * SEQ + (SEQ - 1)];
        float oA = sigf(OO[tokA * H + hcol] + accOA[r]);
        hb[(size_t)bA * H + hcol] = tanhf(cnA[r]) * oA;
        int bB = rowB0 + quad * 4 + r;
        int tokB = x[bB * SEQ + (SEQ - 1)];
        float oB = sigf(OO[tokB * H + hcol] + accOB[r]);
        hb[(size_t)bB * H + hcol] = tanhf(cnB[r]) * oB;
    }
}

// ---------------- p = h @ Wph.T + bp ; out = log_softmax(p) -------------------------------
__global__ __launch_bounds__(128) void out_kernel(
    const float* __restrict__ hbuf, const float* __restrict__ Wph,
    const float* __restrict__ bp, float* __restrict__ out)
{
    const int b = blockIdx.x;
    const int j = threadIdx.x;
    __shared__ float hs[H];
    for (int t = j; t < H; t += 128) hs[t] = hbuf[(size_t)b * H + t];
    __syncthreads();
    const float4* w4 = (const float4*)(Wph + (size_t)j * H);
    const float4* h4 = (const float4*)hs;
    float acc = bp[j];
#pragma unroll 4
    for (int k = 0; k < H / 4; k++) {
        float4 a = w4[k], v = h4[k];
        acc += a.x * v.x + a.y * v.y + a.z * v.z + a.w * v.w;
    }
    __shared__ float red[128];
    red[j] = acc; __syncthreads();
    for (int off = 64; off > 0; off >>= 1) { if (j < off) red[j] = fmaxf(red[j], red[j + off]); __syncthreads(); }
    float m = red[0]; __syncthreads();
    red[j] = __expf(acc - m); __syncthreads();
    for (int off = 64; off > 0; off >>= 1) { if (j < off) red[j] += red[j + off]; __syncthreads(); }
    float lse = m + __logf(red[0]);
    out[(size_t)b * NC + j] = acc - lse;
}

extern "C" void kernel_launch(void* const* d_in, const int* in_sizes, int n_in,
                              void* d_out, int out_size, void* d_ws, size_t ws_size,
                              hipStream_t stream)
{
    const int*   x   = (const int*)d_in[0];
    const float* emb = (const float*)d_in[1];
    const float* Wcx = (const float*)d_in[2];
    const float* bc  = (const float*)d_in[3];
    const float* Wix = (const float*)d_in[4];
    const float* Wih = (const float*)d_in[5];
    const float* bi  = (const float*)d_in[6];
    const float* Wfx = (const float*)d_in[7];
    const float* Wfh = (const float*)d_in[8];
    const float* bf  = (const float*)d_in[9];
    const float* Wox = (const float*)d_in[10];
    const float* Woh = (const float*)d_in[11];
    const float* bo  = (const float*)d_in[12];
    const float* Wph = (const float*)d_in[13];
    const float* bp  = (const float*)d_in[14];
    float* out = (float*)d_out;

    char* wsb = (char*)d_ws;
    float* FF = (float*)(wsb + 0);                         // 512 KB
    float* II = (float*)(wsb + (512 << 10));
    float* OO = (float*)(wsb + (1024 << 10));
    float* G  = (float*)(wsb + (1536 << 10));
    float* hb = (float*)(wsb + (2048 << 10));              // 1 MB
    int*   flags = (int*)(wsb + (3072 << 10));             // 4 KB (16 groups x 64 wave-flags)
    unsigned short* Wf_sw = (unsigned short*)(wsb + (4096 << 10));   // 2 MB each
    unsigned short* Wi_sw = (unsigned short*)(wsb + (6144 << 10));
    unsigned short* Wo_sw = (unsigned short*)(wsb + (8192 << 10));
    unsigned short* c16a  = (unsigned short*)(wsb + (10240 << 10));  // 512 KB each
    unsigned short* c16b  = (unsigned short*)(wsb + (10752 << 10));

    (void)hipMemsetAsync(flags, 0, 4096, stream);   // barrier flags = 0

    tables_kernel<<<dim3(NC, 4), 256, 0, stream>>>(emb, Wcx, bc, Wix, bi, Wfx, bf, Wox, bo,
                                                   FF, II, OO, G);
    swz_kernel<<<512, 256, 0, stream>>>(Wfh, Wf_sw);
    swz_kernel<<<512, 256, 0, stream>>>(Wih, Wi_sw);
    swz_kernel<<<512, 256, 0, stream>>>(Woh, Wo_sw);

    persist_kernel<<<NBLK, 256, 0, stream>>>(Wf_sw, Wi_sw, Wo_sw, FF, II, OO, G, x,
                                             c16a, c16b, hb, flags);

    out_kernel<<<B, 128, 0, stream>>>(hb, Wph, bp, out);
}

// Round 8
// 2406.801 us; speedup vs baseline: 38.6482x; 2.3248x over previous
//
#include <hip/hip_runtime.h>

#define SEQ  512
#define IDIM 256
#define H    1024
#define NC   128
#define B    256
#define NBLK 256   // 16 groups x 16 WGs (16 rows x 64 cols each)

typedef __attribute__((ext_vector_type(8))) short bh8;
typedef __attribute__((ext_vector_type(4))) float f4;
typedef __attribute__((ext_vector_type(4))) int i4;

__device__ __forceinline__ float sigf(float x) { return 1.0f / (1.0f + __expf(-x)); }

__device__ __forceinline__ unsigned short bf16r(float v) {
    unsigned u = __builtin_bit_cast(unsigned, v);
    u += 0x7fffu + ((u >> 16) & 1u);
    return (unsigned short)(u >> 16);
}

// ---------------- token tables: FF/II/OO = emb@W*x.T + b*, G = sigmoid(emb@Wcx.T + bc) ----
__global__ __launch_bounds__(256) void tables_kernel(
    const float* __restrict__ emb,
    const float* __restrict__ Wcx, const float* __restrict__ bc,
    const float* __restrict__ Wix, const float* __restrict__ bi,
    const float* __restrict__ Wfx, const float* __restrict__ bf,
    const float* __restrict__ Wox, const float* __restrict__ bo,
    float* __restrict__ FF, float* __restrict__ II,
    float* __restrict__ OO, float* __restrict__ G)
{
    const int k = blockIdx.x;
    const int h = blockIdx.y * 256 + threadIdx.x;
    __shared__ float e[IDIM];
    e[threadIdx.x] = emb[k * IDIM + threadIdx.x];
    __syncthreads();
    const float4* e4  = (const float4*)e;
    const float4* wf4 = (const float4*)(Wfx + (size_t)h * IDIM);
    const float4* wi4 = (const float4*)(Wix + (size_t)h * IDIM);
    const float4* wo4 = (const float4*)(Wox + (size_t)h * IDIM);
    const float4* wc4 = (const float4*)(Wcx + (size_t)h * IDIM);
    float aF = 0.f, aI = 0.f, aO = 0.f, aC = 0.f;
#pragma unroll 4
    for (int i = 0; i < IDIM / 4; i++) {
        float4 ev = e4[i];
        float4 a = wf4[i]; aF += ev.x * a.x + ev.y * a.y + ev.z * a.z + ev.w * a.w;
        float4 b = wi4[i]; aI += ev.x * b.x + ev.y * b.y + ev.z * b.z + ev.w * b.w;
        float4 c = wo4[i]; aO += ev.x * c.x + ev.y * c.y + ev.z * c.z + ev.w * c.w;
        float4 d = wc4[i]; aC += ev.x * d.x + ev.y * d.y + ev.z * d.z + ev.w * d.w;
    }
    const int o = k * H + h;
    FF[o] = aF + bf[h];
    II[o] = aI + bi[h];
    OO[o] = aO + bo[h];
    G[o]  = sigf(aC + bc[h]);
}

// ---------------- weight fp32 -> bf16 swizzled for MFMA B-fragments -----------------------
__global__ __launch_bounds__(256) void swz_kernel(const float* __restrict__ W,
                                                  unsigned short* __restrict__ D)
{
    int g = blockIdx.x * 256 + threadIdx.x;     // 0..131071
    int h  = g >> 7;
    int kc = (g & 127) << 3;
    const float4* s = (const float4*)(W + (size_t)h * H + kc);
    float4 a = s[0], b = s[1];
    unsigned short tmp[8] = { bf16r(a.x), bf16r(a.y), bf16r(a.z), bf16r(a.w),
                              bf16r(b.x), bf16r(b.y), bf16r(b.z), bf16r(b.w) };
    int nb = h >> 4, kb = kc >> 5, quad = (kc >> 3) & 3;
    int lane = (h & 15) + (quad << 4);
    bh8 v;
#pragma unroll
    for (int j = 0; j < 8; j++) v[j] = (short)tmp[j];
    *(bh8*)(D + (size_t)((nb * 32 + kb) * 512 + lane * 8)) = v;
}

// ------- persistent recurrence: r12 protocol + ARRIVAL COUNTERS + staggered staging ------
// R7 lesson: antiphase serialized (coupled vmcnt); reverted to the proven R0 body.
// This round attacks the flag-observe cost under contention WITHOUT changing semantics:
//   (1) per-(group,step) arrival COUNTER (memset once/launch): each wave's lane 0 posts
//       atomic_add(+1, sc1) after its own drain (same order as R0); consumers poll ONE
//       address until >=64 — a same-address broadcast load (1 LLC line/poll) instead of
//       a 64-lane gather over 4 lines. Monotone per address, distinct address per step:
//       no reset hazards; max skew 1 step; WAR induction identical to R0.
//   (2) s_sleep 1 backoff between failed polls — cuts LLC pressure while waiting.
//   (3) stage reads staggered by WG (start chunk = nt*128, bijective rotation) so the
//       16 WGs of a group don't all hit the same c-buffer lines simultaneously.
__global__ __launch_bounds__(256, 1) void persist_kernel(
    const unsigned short* __restrict__ Wf, const unsigned short* __restrict__ Wi,
    const unsigned short* __restrict__ Wo,
    const float* __restrict__ FF, const float* __restrict__ II,
    const float* __restrict__ OO, const float* __restrict__ G,
    const int* __restrict__ x,
    unsigned short* c16a, unsigned short* c16b,
    float* __restrict__ hb, int* cnts)
{
    const int blk = blockIdx.x;         // 0..255
    const int rt = blk >> 4;            // group 0..15 (16 batch rows) — groups independent
    const int nt = blk & 15;            // 64-col tile 0..15 within group
    const int tid  = threadIdx.x;
    const int wave = tid >> 6;          // wave owns 16 cols, all 16 group rows
    const int lane = tid & 63;
    const int l15 = lane & 15, quad = lane >> 4;

    __shared__ unsigned short cs[16 * 1024];   // 32 KB, XOR-swizzled 16B granules

    const int row0 = rt * 16;
    const int abase = l15 * 1024;              // A-frag row (m = l15)
    const int asw = l15 & 7;
    const int hcol = nt * 64 + wave * 16 + l15;
    const int nb = nt * 4 + wave;              // 16-col weight block 0..63
    const int cofs = nt * 128;                 // staggered staging start (chunks)

    const unsigned short* wfp = Wf + (size_t)nb * 32 * 512 + (size_t)lane * 8;
    const unsigned short* wip = Wi + (size_t)nb * 32 * 512 + (size_t)lane * 8;
    const unsigned short* wop = Wo + (size_t)nb * 32 * 512 + (size_t)lane * 8;

    // loop-invariant F/I weight fragments in VGPRs (1 KB/lane)
    bh8 wf_r[32], wi_r[32];
#pragma unroll
    for (int kt = 0; kt < 32; kt++) {
        wf_r[kt] = *(const bh8*)(wfp + (size_t)kt * 512);
        wi_r[kt] = *(const bh8*)(wip + (size_t)kt * 512);
    }

    float cn_keep[4] = {0.f, 0.f, 0.f, 0.f};   // fp32 cell state in registers
    int* const cnt_g = cnts + rt * SEQ;        // per-group arrival counters [SEQ]

    for (int s = 0; s < SEQ; s++) {
        const unsigned short* cur16 = (s & 1) ? c16b : c16a;
        unsigned short*       nxt16 = (s & 1) ? c16a : c16b;

        // token/table prefetch — in flight while we poll
        float ffv[4], iiv[4], ggv[4];
#pragma unroll
        for (int r = 0; r < 4; r++) {
            int b = row0 + quad * 4 + r;
            int tok = x[b * SEQ + s];
            ffv[r] = FF[tok * H + hcol];
            iiv[r] = II[tok * H + hcol];
            ggv[r] = G[tok * H + hcol];
        }

        f4 accF = {0.f, 0.f, 0.f, 0.f}, accI = {0.f, 0.f, 0.f, 0.f};
        if (s > 0) {
            // poll the step-s arrival counter: one address, broadcast across lanes
            {
                const int* cp = cnt_g + s;
                int guard = 0;
                for (;;) {
                    int fv;
                    asm volatile("global_load_dword %0, %1, off sc0 sc1\n\ts_waitcnt vmcnt(0)"
                                 : "=v"(fv) : "v"(cp) : "memory");
                    if (fv >= 64) break;
                    asm volatile("s_sleep 1");
                    if (++guard > (1 << 20)) break;   // hang bailout (debug)
                }
            }
            // stage 16 rows x 2 KB bf16 of c from LLC: 8 pipelined loads/lane, ONE
            // waitcnt; chunk index rotated by nt so WGs spread over the buffer's lines
            i4 tmp[8];
#pragma unroll
            for (int i = 0; i < 8; i++) {
                int chunk = (i * 256 + tid + cofs) & 2047;   // bijective rotation
                int row = chunk >> 7, g = chunk & 127;
                const i4* p = (const i4*)(cur16 + (size_t)(row0 + row) * H + g * 8);
                asm volatile("global_load_dwordx4 %0, %1, off sc0 sc1"
                             : "=v"(tmp[i]) : "v"(p));
            }
            asm volatile("s_waitcnt vmcnt(0)" ::: "memory");
#pragma unroll
            for (int i = 0; i < 8; i++) {
                int chunk = (i * 256 + tid + cofs) & 2047;
                int row = chunk >> 7, g = chunk & 127;
                *(i4*)(cs + row * 1024 + ((g ^ (row & 7)) << 3)) = tmp[i];
            }
            __syncthreads();   // the ONE per-step WG sync: LDS write -> MFMA read
#pragma unroll
            for (int kt = 0; kt < 32; kt++) {
                bh8 a = *(const bh8*)(cs + abase + (((kt * 4 + quad) ^ asw) << 3));
                accF = __builtin_amdgcn_mfma_f32_16x16x32_bf16(a, wf_r[kt], accF, 0, 0, 0);
                accI = __builtin_amdgcn_mfma_f32_16x16x32_bf16(a, wi_r[kt], accI, 0, 0, 0);
            }
        }

        // epilogue: C/D col=lane&15, row=quad*4+reg; pack 2 cols/dword. Store via
        // NON-RETURNING atomic swap (sc1, no sc0) -> executes at LLC, line stays
        // LLC-resident for the consumers' staging loads.
#pragma unroll
        for (int r = 0; r < 4; r++) {
            float f = sigf(ffv[r] + accF[r]);
            float i = sigf(iiv[r] + accI[r]);
            float cn = ggv[r] * i + cn_keep[r] * f;
            cn_keep[r] = cn;
            int b = row0 + quad * 4 + r;
            unsigned us = bf16r(cn);
            unsigned ot = (unsigned)__shfl_xor((int)us, 1);
            if (s < SEQ - 1 && (lane & 1) == 0) {
                unsigned dw = us | (ot << 16);
                unsigned* p = (unsigned*)(nxt16 + (size_t)b * H + hcol);
                asm volatile("global_atomic_swap %0, %1, off sc1"
                             :: "v"(p), "v"(dw) : "memory");
            }
        }

        if (s < SEQ - 1) {
            // per-wave arrive: drain MY atomics (completed at LLC), bump the step-(s+1)
            // arrival counter (non-returning atomic add at LLC)
            asm volatile("s_waitcnt vmcnt(0)" ::: "memory");
            if (lane == 0) {
                int one = 1;
                int* pc = cnt_g + (s + 1);
                asm volatile("global_atomic_add %0, %1, off sc1"
                             :: "v"(pc), "v"(one) : "memory");
            }
        }
    }

    // o-gate: c_510 still staged in LDS (reference: o uses pre-update cell);
    // Wo streamed from L2 (used once)
    f4 accO = {0.f, 0.f, 0.f, 0.f};
#pragma unroll 4
    for (int kt = 0; kt < 32; kt++) {
        bh8 a  = *(const bh8*)(cs + abase + (((kt * 4 + quad) ^ asw) << 3));
        bh8 bo = *(const bh8*)(wop + (size_t)kt * 512);
        accO = __builtin_amdgcn_mfma_f32_16x16x32_bf16(a, bo, accO, 0, 0, 0);
    }
#pragma unroll
    for (int r = 0; r < 4; r++) {
        int b = row0 + quad * 4 + r;
        int tok = x[b * SEQ + (SEQ - 1)];
        float o = sigf(OO[tok * H + hcol] + accO[r]);
        hb[(size_t)b * H + hcol] = tanhf(cn_keep[r]) * o;
    }
}

// ---------------- p = h @ Wph.T + bp ; out = log_softmax(p) -------------------------------
__global__ __launch_bounds__(128) void out_kernel(
    const float* __restrict__ hbuf, const float* __restrict__ Wph,
    const float* __restrict__ bp, float* __restrict__ out)
{
    const int b = blockIdx.x;
    const int j = threadIdx.x;
    __shared__ float hs[H];
    for (int t = j; t < H; t += 128) hs[t] = hbuf[(size_t)b * H + t];
    __syncthreads();
    const float4* w4 = (const float4*)(Wph + (size_t)j * H);
    const float4* h4 = (const float4*)hs;
    float acc = bp[j];
#pragma unroll 4
    for (int k = 0; k < H / 4; k++) {
        float4 a = w4[k], v = h4[k];
        acc += a.x * v.x + a.y * v.y + a.z * v.z + a.w * v.w;
    }
    __shared__ float red[128];
    red[j] = acc; __syncthreads();
    for (int off = 64; off > 0; off >>= 1) { if (j < off) red[j] = fmaxf(red[j], red[j + off]); __syncthreads(); }
    float m = red[0]; __syncthreads();
    red[j] = __expf(acc - m); __syncthreads();
    for (int off = 64; off > 0; off >>= 1) { if (j < off) red[j] += red[j + off]; __syncthreads(); }
    float lse = m + __logf(red[0]);
    out[(size_t)b * NC + j] = acc - lse;
}

extern "C" void kernel_launch(void* const* d_in, const int* in_sizes, int n_in,
                              void* d_out, int out_size, void* d_ws, size_t ws_size,
                              hipStream_t stream)
{
    const int*   x   = (const int*)d_in[0];
    const float* emb = (const float*)d_in[1];
    const float* Wcx = (const float*)d_in[2];
    const float* bc  = (const float*)d_in[3];
    const float* Wix = (const float*)d_in[4];
    const float* Wih = (const float*)d_in[5];
    const float* bi  = (const float*)d_in[6];
    const float* Wfx = (const float*)d_in[7];
    const float* Wfh = (const float*)d_in[8];
    const float* bf  = (const float*)d_in[9];
    const float* Wox = (const float*)d_in[10];
    const float* Woh = (const float*)d_in[11];
    const float* bo  = (const float*)d_in[12];
    const float* Wph = (const float*)d_in[13];
    const float* bp  = (const float*)d_in[14];
    float* out = (float*)d_out;

    char* wsb = (char*)d_ws;
    float* FF = (float*)(wsb + 0);                         // 512 KB
    float* II = (float*)(wsb + (512 << 10));
    float* OO = (float*)(wsb + (1024 << 10));
    float* G  = (float*)(wsb + (1536 << 10));
    float* hb = (float*)(wsb + (2048 << 10));              // 1 MB
    int*   cnts = (int*)(wsb + (3072 << 10));              // 32 KB (16 groups x 512 counters)
    unsigned short* Wf_sw = (unsigned short*)(wsb + (4096 << 10));   // 2 MB each
    unsigned short* Wi_sw = (unsigned short*)(wsb + (6144 << 10));
    unsigned short* Wo_sw = (unsigned short*)(wsb + (8192 << 10));
    unsigned short* c16a  = (unsigned short*)(wsb + (10240 << 10));  // 512 KB each
    unsigned short* c16b  = (unsigned short*)(wsb + (10752 << 10));

    (void)hipMemsetAsync(cnts, 0, 16 * SEQ * sizeof(int), stream);   // arrival counters = 0

    tables_kernel<<<dim3(NC, 4), 256, 0, stream>>>(emb, Wcx, bc, Wix, bi, Wfx, bf, Wox, bo,
                                                   FF, II, OO, G);
    swz_kernel<<<512, 256, 0, stream>>>(Wfh, Wf_sw);
    swz_kernel<<<512, 256, 0, stream>>>(Wih, Wi_sw);
    swz_kernel<<<512, 256, 0, stream>>>(Woh, Wo_sw);

    persist_kernel<<<NBLK, 256, 0, stream>>>(Wf_sw, Wi_sw, Wo_sw, FF, II, OO, G, x,
                                             c16a, c16b, hb, cnts);

    out_kernel<<<B, 128, 0, stream>>>(hb, Wph, bp, out);
}

// Round 9
// 2393.624 us; speedup vs baseline: 38.8610x; 1.0055x over previous
//
#include <hip/hip_runtime.h>

#define SEQ  512
#define IDIM 256
#define H    1024
#define NC   128
#define B    256
#define NBLK 256   // 16 groups x 16 WGs (16 rows x 64 cols each)

typedef __attribute__((ext_vector_type(8))) short bh8;
typedef __attribute__((ext_vector_type(4))) float f4;
typedef __attribute__((ext_vector_type(4))) int i4;

__device__ __forceinline__ float sigf(float x) { return 1.0f / (1.0f + __expf(-x)); }

__device__ __forceinline__ unsigned short bf16r(float v) {
    unsigned u = __builtin_bit_cast(unsigned, v);
    u += 0x7fffu + ((u >> 16) & 1u);
    return (unsigned short)(u >> 16);
}

// ---------------- token tables: FF/II/OO = emb@W*x.T + b*, G = sigmoid(emb@Wcx.T + bc) ----
__global__ __launch_bounds__(256) void tables_kernel(
    const float* __restrict__ emb,
    const float* __restrict__ Wcx, const float* __restrict__ bc,
    const float* __restrict__ Wix, const float* __restrict__ bi,
    const float* __restrict__ Wfx, const float* __restrict__ bf,
    const float* __restrict__ Wox, const float* __restrict__ bo,
    float* __restrict__ FF, float* __restrict__ II,
    float* __restrict__ OO, float* __restrict__ G)
{
    const int k = blockIdx.x;
    const int h = blockIdx.y * 256 + threadIdx.x;
    __shared__ float e[IDIM];
    e[threadIdx.x] = emb[k * IDIM + threadIdx.x];
    __syncthreads();
    const float4* e4  = (const float4*)e;
    const float4* wf4 = (const float4*)(Wfx + (size_t)h * IDIM);
    const float4* wi4 = (const float4*)(Wix + (size_t)h * IDIM);
    const float4* wo4 = (const float4*)(Wox + (size_t)h * IDIM);
    const float4* wc4 = (const float4*)(Wcx + (size_t)h * IDIM);
    float aF = 0.f, aI = 0.f, aO = 0.f, aC = 0.f;
#pragma unroll 4
    for (int i = 0; i < IDIM / 4; i++) {
        float4 ev = e4[i];
        float4 a = wf4[i]; aF += ev.x * a.x + ev.y * a.y + ev.z * a.z + ev.w * a.w;
        float4 b = wi4[i]; aI += ev.x * b.x + ev.y * b.y + ev.z * b.z + ev.w * b.w;
        float4 c = wo4[i]; aO += ev.x * c.x + ev.y * c.y + ev.z * c.z + ev.w * c.w;
        float4 d = wc4[i]; aC += ev.x * d.x + ev.y * d.y + ev.z * d.z + ev.w * d.w;
    }
    const int o = k * H + h;
    FF[o] = aF + bf[h];
    II[o] = aI + bi[h];
    OO[o] = aO + bo[h];
    G[o]  = sigf(aC + bc[h]);
}

// ---------------- weight fp32 -> bf16 swizzled for MFMA B-fragments -----------------------
__global__ __launch_bounds__(256) void swz_kernel(const float* __restrict__ W,
                                                  unsigned short* __restrict__ D)
{
    int g = blockIdx.x * 256 + threadIdx.x;     // 0..131071
    int h  = g >> 7;
    int kc = (g & 127) << 3;
    const float4* s = (const float4*)(W + (size_t)h * H + kc);
    float4 a = s[0], b = s[1];
    unsigned short tmp[8] = { bf16r(a.x), bf16r(a.y), bf16r(a.z), bf16r(a.w),
                              bf16r(b.x), bf16r(b.y), bf16r(b.z), bf16r(b.w) };
    int nb = h >> 4, kb = kc >> 5, quad = (kc >> 3) & 3;
    int lane = (h & 15) + (quad << 4);
    bh8 v;
#pragma unroll
    for (int j = 0; j < 8; j++) v[j] = (short)tmp[j];
    *(bh8*)(D + (size_t)((nb * 32 + kb) * 512 + lane * 8)) = v;
}

// ------- persistent recurrence: r12 protocol + PACKED x2 ATOMICS + per-WG post -----------
// R8 (counter poll, sleep, stagger) was NEUTRAL -> observe-side mechanics are not the
// cost. R1/R7 bracketed the chain as producer-tail latency. This round halves the
// producer-side transaction count with identical semantics:
//   (1) global_atomic_swap_x2: 4 cols per atomic (one extra shfl_xor to pack 64 bits)
//       -> 256 atomics/WG/step instead of 512; the in-order vmcnt drain tail halves.
//   (2) per-WG arrival: waves drain own atomics in parallel, ONE syncthreads, single
//       +1 bump; consumers poll counter >= 16 (was 64) -> 4x fewer straggling posts.
// WAR induction unchanged: a WG's bump implies all its waves drained step-s writes and
// completed their step-s staging reads (stage precedes MFMA precedes epilogue).
__global__ __launch_bounds__(256, 1) void persist_kernel(
    const unsigned short* __restrict__ Wf, const unsigned short* __restrict__ Wi,
    const unsigned short* __restrict__ Wo,
    const float* __restrict__ FF, const float* __restrict__ II,
    const float* __restrict__ OO, const float* __restrict__ G,
    const int* __restrict__ x,
    unsigned short* c16a, unsigned short* c16b,
    float* __restrict__ hb, int* cnts)
{
    const int blk = blockIdx.x;         // 0..255
    const int rt = blk >> 4;            // group 0..15 (16 batch rows) — groups independent
    const int nt = blk & 15;            // 64-col tile 0..15 within group
    const int tid  = threadIdx.x;
    const int wave = tid >> 6;          // wave owns 16 cols, all 16 group rows
    const int lane = tid & 63;
    const int l15 = lane & 15, quad = lane >> 4;

    __shared__ unsigned short cs[16 * 1024];   // 32 KB, XOR-swizzled 16B granules

    const int row0 = rt * 16;
    const int abase = l15 * 1024;              // A-frag row (m = l15)
    const int asw = l15 & 7;
    const int hcol = nt * 64 + wave * 16 + l15;
    const int nb = nt * 4 + wave;              // 16-col weight block 0..63
    const int cofs = nt * 128;                 // staggered staging start (chunks)

    const unsigned short* wfp = Wf + (size_t)nb * 32 * 512 + (size_t)lane * 8;
    const unsigned short* wip = Wi + (size_t)nb * 32 * 512 + (size_t)lane * 8;
    const unsigned short* wop = Wo + (size_t)nb * 32 * 512 + (size_t)lane * 8;

    // loop-invariant F/I weight fragments in VGPRs (1 KB/lane)
    bh8 wf_r[32], wi_r[32];
#pragma unroll
    for (int kt = 0; kt < 32; kt++) {
        wf_r[kt] = *(const bh8*)(wfp + (size_t)kt * 512);
        wi_r[kt] = *(const bh8*)(wip + (size_t)kt * 512);
    }

    float cn_keep[4] = {0.f, 0.f, 0.f, 0.f};   // fp32 cell state in registers
    int* const cnt_g = cnts + rt * SEQ;        // per-group arrival counters [SEQ]

    for (int s = 0; s < SEQ; s++) {
        const unsigned short* cur16 = (s & 1) ? c16b : c16a;
        unsigned short*       nxt16 = (s & 1) ? c16a : c16b;

        // token/table prefetch — in flight while we poll
        float ffv[4], iiv[4], ggv[4];
#pragma unroll
        for (int r = 0; r < 4; r++) {
            int b = row0 + quad * 4 + r;
            int tok = x[b * SEQ + s];
            ffv[r] = FF[tok * H + hcol];
            iiv[r] = II[tok * H + hcol];
            ggv[r] = G[tok * H + hcol];
        }

        f4 accF = {0.f, 0.f, 0.f, 0.f}, accI = {0.f, 0.f, 0.f, 0.f};
        if (s > 0) {
            // poll the step-s arrival counter: one address, broadcast across lanes
            {
                const int* cp = cnt_g + s;
                int guard = 0;
                for (;;) {
                    int fv;
                    asm volatile("global_load_dword %0, %1, off sc0 sc1\n\ts_waitcnt vmcnt(0)"
                                 : "=v"(fv) : "v"(cp) : "memory");
                    if (fv >= 16) break;
                    asm volatile("s_sleep 1");
                    if (++guard > (1 << 20)) break;   // hang bailout (debug)
                }
            }
            // stage 16 rows x 2 KB bf16 of c from LLC: 8 pipelined loads/lane, ONE
            // waitcnt; chunk index rotated by nt so WGs spread over the buffer's lines
            i4 tmp[8];
#pragma unroll
            for (int i = 0; i < 8; i++) {
                int chunk = (i * 256 + tid + cofs) & 2047;   // bijective rotation
                int row = chunk >> 7, g = chunk & 127;
                const i4* p = (const i4*)(cur16 + (size_t)(row0 + row) * H + g * 8);
                asm volatile("global_load_dwordx4 %0, %1, off sc0 sc1"
                             : "=v"(tmp[i]) : "v"(p));
            }
            asm volatile("s_waitcnt vmcnt(0)" ::: "memory");
#pragma unroll
            for (int i = 0; i < 8; i++) {
                int chunk = (i * 256 + tid + cofs) & 2047;
                int row = chunk >> 7, g = chunk & 127;
                *(i4*)(cs + row * 1024 + ((g ^ (row & 7)) << 3)) = tmp[i];
            }
            __syncthreads();   // the ONE per-step WG sync: LDS write -> MFMA read
#pragma unroll
            for (int kt = 0; kt < 32; kt++) {
                bh8 a = *(const bh8*)(cs + abase + (((kt * 4 + quad) ^ asw) << 3));
                accF = __builtin_amdgcn_mfma_f32_16x16x32_bf16(a, wf_r[kt], accF, 0, 0, 0);
                accI = __builtin_amdgcn_mfma_f32_16x16x32_bf16(a, wi_r[kt], accI, 0, 0, 0);
            }
        }

        // epilogue: C/D col=lane&15, row=quad*4+reg; pack 4 cols per 64-bit atomic.
        // Store via NON-RETURNING atomic swap_x2 (sc1) -> executes at LLC, line stays
        // LLC-resident for the consumers' staging loads; half the queue depth of x1.
#pragma unroll
        for (int r = 0; r < 4; r++) {
            float f = sigf(ffv[r] + accF[r]);
            float i = sigf(iiv[r] + accI[r]);
            float cn = ggv[r] * i + cn_keep[r] * f;
            cn_keep[r] = cn;
            int b = row0 + quad * 4 + r;
            unsigned us = bf16r(cn);
            unsigned ot = (unsigned)__shfl_xor((int)us, 1);
            unsigned dw = us | (ot << 16);                       // cols (c, c+1) on even lanes
            unsigned dwhi = (unsigned)__shfl_xor((int)dw, 2);    // cols (c+2, c+3) from lane+2
            if (s < SEQ - 1 && (lane & 3) == 0) {
                unsigned long long qw = (unsigned long long)dw
                                      | ((unsigned long long)dwhi << 32);
                unsigned long long* p = (unsigned long long*)(nxt16 + (size_t)b * H + hcol);
                asm volatile("global_atomic_swap_x2 %0, %1, off sc1"
                             :: "v"(p), "v"(qw) : "memory");
            }
        }

        if (s < SEQ - 1) {
            // per-WG arrive: each wave drains its own atomics (parallel), one intra-WG
            // sync, then a single +1 bump of the step-(s+1) counter (at LLC)
            asm volatile("s_waitcnt vmcnt(0)" ::: "memory");
            __syncthreads();
            if (tid == 0) {
                int one = 1;
                int* pc = cnt_g + (s + 1);
                asm volatile("global_atomic_add %0, %1, off sc1"
                             :: "v"(pc), "v"(one) : "memory");
            }
        }
    }

    // o-gate: c_510 still staged in LDS (reference: o uses pre-update cell);
    // Wo streamed from L2 (used once)
    f4 accO = {0.f, 0.f, 0.f, 0.f};
#pragma unroll 4
    for (int kt = 0; kt < 32; kt++) {
        bh8 a  = *(const bh8*)(cs + abase + (((kt * 4 + quad) ^ asw) << 3));
        bh8 bo = *(const bh8*)(wop + (size_t)kt * 512);
        accO = __builtin_amdgcn_mfma_f32_16x16x32_bf16(a, bo, accO, 0, 0, 0);
    }
#pragma unroll
    for (int r = 0; r < 4; r++) {
        int b = row0 + quad * 4 + r;
        int tok = x[b * SEQ + (SEQ - 1)];
        float o = sigf(OO[tok * H + hcol] + accO[r]);
        hb[(size_t)b * H + hcol] = tanhf(cn_keep[r]) * o;
    }
}

// ---------------- p = h @ Wph.T + bp ; out = log_softmax(p) -------------------------------
__global__ __launch_bounds__(128) void out_kernel(
    const float* __restrict__ hbuf, const float* __restrict__ Wph,
    const float* __restrict__ bp, float* __restrict__ out)
{
    const int b = blockIdx.x;
    const int j = threadIdx.x;
    __shared__ float hs[H];
    for (int t = j; t < H; t += 128) hs[t] = hbuf[(size_t)b * H + t];
    __syncthreads();
    const float4* w4 = (const float4*)(Wph + (size_t)j * H);
    const float4* h4 = (const float4*)hs;
    float acc = bp[j];
#pragma unroll 4
    for (int k = 0; k < H / 4; k++) {
        float4 a = w4[k], v = h4[k];
        acc += a.x * v.x + a.y * v.y + a.z * v.z + a.w * v.w;
    }
    __shared__ float red[128];
    red[j] = acc; __syncthreads();
    for (int off = 64; off > 0; off >>= 1) { if (j < off) red[j] = fmaxf(red[j], red[j + off]); __syncthreads(); }
    float m = red[0]; __syncthreads();
    red[j] = __expf(acc - m); __syncthreads();
    for (int off = 64; off > 0; off >>= 1) { if (j < off) red[j] += red[j + off]; __syncthreads(); }
    float lse = m + __logf(red[0]);
    out[(size_t)b * NC + j] = acc - lse;
}

extern "C" void kernel_launch(void* const* d_in, const int* in_sizes, int n_in,
                              void* d_out, int out_size, void* d_ws, size_t ws_size,
                              hipStream_t stream)
{
    const int*   x   = (const int*)d_in[0];
    const float* emb = (const float*)d_in[1];
    const float* Wcx = (const float*)d_in[2];
    const float* bc  = (const float*)d_in[3];
    const float* Wix = (const float*)d_in[4];
    const float* Wih = (const float*)d_in[5];
    const float* bi  = (const float*)d_in[6];
    const float* Wfx = (const float*)d_in[7];
    const float* Wfh = (const float*)d_in[8];
    const float* bf  = (const float*)d_in[9];
    const float* Wox = (const float*)d_in[10];
    const float* Woh = (const float*)d_in[11];
    const float* bo  = (const float*)d_in[12];
    const float* Wph = (const float*)d_in[13];
    const float* bp  = (const float*)d_in[14];
    float* out = (float*)d_out;

    char* wsb = (char*)d_ws;
    float* FF = (float*)(wsb + 0);                         // 512 KB
    float* II = (float*)(wsb + (512 << 10));
    float* OO = (float*)(wsb + (1024 << 10));
    float* G  = (float*)(wsb + (1536 << 10));
    float* hb = (float*)(wsb + (2048 << 10));              // 1 MB
    int*   cnts = (int*)(wsb + (3072 << 10));              // 32 KB (16 groups x 512 counters)
    unsigned short* Wf_sw = (unsigned short*)(wsb + (4096 << 10));   // 2 MB each
    unsigned short* Wi_sw = (unsigned short*)(wsb + (6144 << 10));
    unsigned short* Wo_sw = (unsigned short*)(wsb + (8192 << 10));
    unsigned short* c16a  = (unsigned short*)(wsb + (10240 << 10));  // 512 KB each
    unsigned short* c16b  = (unsigned short*)(wsb + (10752 << 10));

    (void)hipMemsetAsync(cnts, 0, 16 * SEQ * sizeof(int), stream);   // arrival counters = 0

    tables_kernel<<<dim3(NC, 4), 256, 0, stream>>>(emb, Wcx, bc, Wix, bi, Wfx, bf, Wox, bo,
                                                   FF, II, OO, G);
    swz_kernel<<<512, 256, 0, stream>>>(Wfh, Wf_sw);
    swz_kernel<<<512, 256, 0, stream>>>(Wih, Wi_sw);
    swz_kernel<<<512, 256, 0, stream>>>(Woh, Wo_sw);

    persist_kernel<<<NBLK, 256, 0, stream>>>(Wf_sw, Wi_sw, Wo_sw, FF, II, OO, G, x,
                                             c16a, c16b, hb, cnts);

    out_kernel<<<B, 128, 0, stream>>>(hb, Wph, bp, out);
}